// Round 2
// baseline (601.161 us; speedup 1.0000x reference)
//
#include <hip/hip_runtime.h>

// GCN 2-layer + mean-pool + FC for MI355X (gfx950).
// Round 2: replace atomic scatter (k_agg2, 38.4M f32 atomics, 150MB HBM write)
// with per-call CSR build + gather aggregation (no f32 atomics on the hot path).
//
// Pipeline:
//   cnt[i]   = indeg(i)                      (int histogram)
//   scan: row_start = exclusive_scan(cnt); cursor = row_start; dis = rsqrt(cnt+1)
//   scatter: eidx[pos]=src, enorm[pos]=dis[s]*dis[d]  (CSR by dst)
//            + aggx[d] += x[s]*norm          (layer-1 aggregate, 3 floats/edge)
//   t[i,:]   = relu((aggx[i]+x[i]*dis^2) @ W1 + b1) @ W2   (fused, weights in LDS)
//   gather:  h2[i,:] = relu(sum_{s in N(i)} t[s,:]*enorm + t[i,:]*dis^2 + b2)
//            gacc    += column-sums of h2    (fused mean pool)
//   out = gacc/N @ Wfc + bfc

#define N_SCAN_THREADS 1024

__global__ void k_count(const int* __restrict__ dst, int* __restrict__ cnt, int E) {
    for (int e = blockIdx.x * blockDim.x + threadIdx.x; e < E; e += gridDim.x * blockDim.x)
        atomicAdd(&cnt[dst[e]], 1);
}

// Single-block exclusive scan over cnt[0..n); also emits dis = rsqrt(cnt+1) and cursor copy.
__global__ void k_scan(const int* __restrict__ cnt, int* __restrict__ row_start,
                       int* __restrict__ cursor, float* __restrict__ dis, int n) {
    __shared__ int part[N_SCAN_THREADS];
    int tid = threadIdx.x;
    int chunk = (n + N_SCAN_THREADS - 1) / N_SCAN_THREADS;
    int lo = tid * chunk;
    int hi = min(lo + chunk, n);
    int s = 0;
    for (int i = lo; i < hi; ++i) s += cnt[i];
    part[tid] = s;
    __syncthreads();
    // Hillis-Steele inclusive scan over partials
    for (int off = 1; off < N_SCAN_THREADS; off <<= 1) {
        int v = (tid >= off) ? part[tid - off] : 0;
        __syncthreads();
        part[tid] += v;
        __syncthreads();
    }
    int run = (tid > 0) ? part[tid - 1] : 0;
    for (int i = lo; i < hi; ++i) {
        row_start[i] = run;
        cursor[i] = run;
        dis[i] = rsqrtf((float)cnt[i] + 1.0f);
        run += cnt[i];
    }
    if (lo < n && hi == n) row_start[n] = run;   // == E
}

// CSR scatter + layer-1 feature aggregation (3 floats/edge, small atomic volume).
__global__ void k_scatter_aggx(const int* __restrict__ src, const int* __restrict__ dst,
                               const float* __restrict__ x, const float* __restrict__ dis,
                               int* __restrict__ cursor, int* __restrict__ eidx,
                               float* __restrict__ enorm, float* __restrict__ aggx, int E) {
    for (int e = blockIdx.x * blockDim.x + threadIdx.x; e < E; e += gridDim.x * blockDim.x) {
        int s = src[e], d = dst[e];
        float nrm = dis[s] * dis[d];
        int pos = atomicAdd(&cursor[d], 1);
        eidx[pos] = s;
        enorm[pos] = nrm;
        atomicAdd(&aggx[d * 3 + 0], x[s * 3 + 0] * nrm);
        atomicAdd(&aggx[d * 3 + 1], x[s * 3 + 1] * nrm);
        atomicAdd(&aggx[d * 3 + 2], x[s * 3 + 2] * nrm);
    }
}

// t[i,k] = sum_j relu( a(i) . W1[:,j] + b1[j] ) * W2[j,k],  a(i) = aggx[i] + x[i]*dis[i]^2
// One wave per node; lane k owns output feature k. W1/b1/W2 staged in LDS (34 KB).
__global__ void k_node_t(const float* __restrict__ x, const float* __restrict__ dis,
                         const float* __restrict__ aggx,
                         const float* __restrict__ W1, const float* __restrict__ b1,
                         const float* __restrict__ W2,
                         float* __restrict__ t, int n) {
    __shared__ float sW1[3 * 128];
    __shared__ float sb1[128];
    __shared__ float sW2[128 * 64];
    for (int i = threadIdx.x; i < 3 * 128; i += blockDim.x) sW1[i] = W1[i];
    for (int i = threadIdx.x; i < 128;     i += blockDim.x) sb1[i] = b1[i];
    for (int i = threadIdx.x; i < 128 * 64; i += blockDim.x) sW2[i] = W2[i];
    __syncthreads();

    int lane = threadIdx.x & 63;
    int gw = (blockIdx.x * blockDim.x + threadIdx.x) >> 6;
    int nw = (gridDim.x * blockDim.x) >> 6;
    for (int i = gw; i < n; i += nw) {
        float d2 = dis[i] * dis[i];
        float a0 = aggx[i * 3 + 0] + x[i * 3 + 0] * d2;
        float a1 = aggx[i * 3 + 1] + x[i * 3 + 1] * d2;
        float a2 = aggx[i * 3 + 2] + x[i * 3 + 2] * d2;
        float acc = 0.0f;
        #pragma unroll 8
        for (int j = 0; j < 128; ++j) {
            float h = fmaxf(fmaf(a0, sW1[j], fmaf(a1, sW1[128 + j], fmaf(a2, sW1[256 + j], sb1[j]))), 0.0f);
            acc = fmaf(h, sW2[j * 64 + lane], acc);
        }
        t[(size_t)i * 64 + lane] = acc;
    }
}

// Gather aggregation for layer 2 + relu + fused mean pool. One wave per node.
__global__ void k_agg2_gather(const int* __restrict__ row_start, const int* __restrict__ eidx,
                              const float* __restrict__ enorm, const float* __restrict__ t,
                              const float* __restrict__ dis, const float* __restrict__ b2,
                              float* __restrict__ gacc, int n) {
    int lane = threadIdx.x & 63;
    float bk = b2[lane];
    int gw = (blockIdx.x * blockDim.x + threadIdx.x) >> 6;
    int nw = (gridDim.x * blockDim.x) >> 6;
    float acc_g = 0.0f;
    for (int i = gw; i < n; i += nw) {
        float d2 = dis[i] * dis[i];
        float acc = t[(size_t)i * 64 + lane] * d2;   // self-loop term
        int p = row_start[i], p1 = row_start[i + 1];
        // 2-way unroll: two independent t-row loads in flight
        for (; p + 1 < p1; p += 2) {
            int s0 = eidx[p], s1 = eidx[p + 1];
            float n0 = enorm[p], n1 = enorm[p + 1];
            float v0 = t[(size_t)s0 * 64 + lane];
            float v1 = t[(size_t)s1 * 64 + lane];
            acc = fmaf(v0, n0, acc);
            acc = fmaf(v1, n1, acc);
        }
        if (p < p1) {
            int s0 = eidx[p];
            acc = fmaf(t[(size_t)s0 * 64 + lane], enorm[p], acc);
        }
        acc_g += fmaxf(acc + bk, 0.0f);
    }
    atomicAdd(&gacc[lane], acc_g);
}

// out[c] = (1/N) * sum_k g[k] * Wfc[k,c] + bfc[c]; single wave.
__global__ void k_final(const float* __restrict__ g_accum, const float* __restrict__ Wfc,
                        const float* __restrict__ bfc, float* __restrict__ out, float inv_n) {
    int lane = threadIdx.x;   // 0..63
    float gk = g_accum[lane] * inv_n;
    #pragma unroll
    for (int c = 0; c < 3; ++c) {
        float p = gk * Wfc[lane * 3 + c];
        #pragma unroll
        for (int off = 32; off > 0; off >>= 1) p += __shfl_down(p, off);
        if (lane == 0) out[c] = p + bfc[c];
    }
}

extern "C" void kernel_launch(void* const* d_in, const int* in_sizes, int n_in,
                              void* d_out, int out_size, void* d_ws, size_t ws_size,
                              hipStream_t stream) {
    const float* x   = (const float*)d_in[0];
    const int*   ei  = (const int*)d_in[1];
    const float* W1  = (const float*)d_in[2];
    const float* b1  = (const float*)d_in[3];
    const float* W2  = (const float*)d_in[4];
    const float* b2  = (const float*)d_in[5];
    const float* Wfc = (const float*)d_in[6];
    const float* bfc = (const float*)d_in[7];

    const int N = in_sizes[0] / 3;      // 50000
    const int E = in_sizes[1] / 2;      // 600000
    const int* src = ei;
    const int* dst = ei + E;

    // Workspace layout (floats/ints, 4B each):
    //   dis       : N            @ 0
    //   aggx      : 3N           @ N        (zeroed)
    //   gacc      : 64           @ 4N       (zeroed)
    //   cnt       : N (int)      @ 4N+64    (zeroed)
    //   row_start : N+1 (int)    @ 5N+64
    //   cursor    : N (int)      @ 6N+65
    //   eidx      : E (int)      @ 7N+65
    //   enorm     : E            @ 7N+65+E
    //   t         : 64N          @ 7N+65+2E
    float* ws = (float*)d_ws;
    float* dis   = ws;
    float* aggx  = ws + (size_t)N;
    float* gacc  = ws + (size_t)4 * N;
    int*   cnt   = (int*)(ws + (size_t)4 * N + 64);
    int*   rs    = (int*)(ws + (size_t)5 * N + 64);
    int*   cur   = (int*)(ws + (size_t)6 * N + 65);
    int*   eidx  = (int*)(ws + (size_t)7 * N + 65);
    float* enorm = ws + (size_t)7 * N + 65 + (size_t)E;
    float* t     = ws + (size_t)7 * N + 65 + (size_t)2 * E;

    // zero aggx + gacc + cnt in one contiguous memset
    hipMemsetAsync(aggx, 0, ((size_t)4 * N + 64) * sizeof(float), stream);

    k_count<<<1024, 256, 0, stream>>>(dst, cnt, E);
    k_scan<<<1, N_SCAN_THREADS, 0, stream>>>(cnt, rs, cur, dis, N);
    k_scatter_aggx<<<1024, 256, 0, stream>>>(src, dst, x, dis, cur, eidx, enorm, aggx, E);
    k_node_t<<<1024, 256, 0, stream>>>(x, dis, aggx, W1, b1, W2, t, N);
    k_agg2_gather<<<2048, 256, 0, stream>>>(rs, eidx, enorm, t, dis, b2, gacc, N);
    k_final<<<1, 64, 0, stream>>>(gacc, Wfc, bfc, (float*)d_out, 1.0f / (float)N);
}

// Round 3
// 347.819 us; speedup vs baseline: 1.7284x; 1.7284x over previous
//
#include <hip/hip_runtime.h>

// GCN 2-layer + mean-pool + FC for MI355X (gfx950).
// Round 3: MLP-optimized gather (16 lanes/node, float4, 4-edge unroll),
// pure CSR build (no f32 atomics), layer-1 aggregate fused into node kernel.
//
// Pipeline:
//   cnt = indeg; scan -> row_start/cursor, dis = rsqrt(cnt+1)
//   csr: eidx[pos]=src, enorm[pos]=dis[s]*dis[d]
//   node: a(i) = gather_x + x[i]*dis^2 ; t[i,:] = relu(a@W1+b1)@W2  (weights in LDS)
//   gather2: h2[i,:]=relu(sum t[s,:]*enorm + t[i,:]*dis^2 + b2); gacc += colsum(h2)
//   out = gacc/N @ Wfc + bfc

#define SCAN_THREADS 1024

__global__ void k_count(const int* __restrict__ dst, int* __restrict__ cnt, int E) {
    for (int e = blockIdx.x * blockDim.x + threadIdx.x; e < E; e += gridDim.x * blockDim.x)
        atomicAdd(&cnt[dst[e]], 1);
}

// Single-block exclusive scan; emits row_start, cursor copy, dis = rsqrt(deg).
__global__ void k_scan(const int* __restrict__ cnt, int* __restrict__ rs,
                       int* __restrict__ cur, float* __restrict__ dis, int n) {
    __shared__ int part[SCAN_THREADS];
    int tid = threadIdx.x;
    int chunk = (n + SCAN_THREADS - 1) / SCAN_THREADS;
    int lo = min(tid * chunk, n);
    int hi = min(lo + chunk, n);
    int s = 0;
    for (int i = lo; i < hi; ++i) s += cnt[i];
    part[tid] = s;
    __syncthreads();
    for (int off = 1; off < SCAN_THREADS; off <<= 1) {
        int v = (tid >= off) ? part[tid - off] : 0;
        __syncthreads();
        part[tid] += v;
        __syncthreads();
    }
    int run = (tid > 0) ? part[tid - 1] : 0;
    for (int i = lo; i < hi; ++i) {
        rs[i] = run;
        cur[i] = run;
        dis[i] = rsqrtf((float)cnt[i] + 1.0f);
        run += cnt[i];
    }
    if (tid == SCAN_THREADS - 1) rs[n] = part[SCAN_THREADS - 1];   // == E
}

// Pure CSR scatter (int cursor atomics only).
__global__ void k_csr(const int* __restrict__ src, const int* __restrict__ dst,
                      const float* __restrict__ dis, int* __restrict__ cur,
                      int* __restrict__ eidx, float* __restrict__ enorm, int E) {
    for (int e = blockIdx.x * blockDim.x + threadIdx.x; e < E; e += gridDim.x * blockDim.x) {
        int s = src[e], d = dst[e];
        int pos = atomicAdd(&cur[d], 1);
        eidx[pos] = s;
        enorm[pos] = dis[s] * dis[d];
    }
}

// Fused: layer-1 gather (lane-per-edge + shfl reduce) + MLP to t.
// One wave per node; lane k owns output feature k. W1/b1/W2 in LDS (34 KB).
__global__ void k_node_t(const float* __restrict__ x, const float* __restrict__ dis,
                         const int* __restrict__ rs, const int* __restrict__ eidx,
                         const float* __restrict__ enorm,
                         const float* __restrict__ W1, const float* __restrict__ b1,
                         const float* __restrict__ W2,
                         float* __restrict__ t, int n) {
    __shared__ float sW1[3 * 128];
    __shared__ float sb1[128];
    __shared__ float sW2[128 * 64];
    for (int i = threadIdx.x; i < 3 * 128;  i += blockDim.x) sW1[i] = W1[i];
    for (int i = threadIdx.x; i < 128;      i += blockDim.x) sb1[i] = b1[i];
    for (int i = threadIdx.x; i < 128 * 64; i += blockDim.x) sW2[i] = W2[i];
    __syncthreads();

    int lane = threadIdx.x & 63;
    int gw = (blockIdx.x * blockDim.x + threadIdx.x) >> 6;
    int nw = (gridDim.x * blockDim.x) >> 6;
    for (int i = gw; i < n; i += nw) {
        int p0 = rs[i], p1 = rs[i + 1];
        float a0 = 0.f, a1 = 0.f, a2 = 0.f;
        for (int p = p0 + lane; p < p1; p += 64) {
            int s = eidx[p];
            float nm = enorm[p];
            a0 = fmaf(x[3 * s + 0], nm, a0);
            a1 = fmaf(x[3 * s + 1], nm, a1);
            a2 = fmaf(x[3 * s + 2], nm, a2);
        }
        #pragma unroll
        for (int m = 32; m; m >>= 1) {
            a0 += __shfl_xor(a0, m);
            a1 += __shfl_xor(a1, m);
            a2 += __shfl_xor(a2, m);
        }
        float di = dis[i], d2 = di * di;
        a0 = fmaf(x[3 * i + 0], d2, a0);
        a1 = fmaf(x[3 * i + 1], d2, a1);
        a2 = fmaf(x[3 * i + 2], d2, a2);
        float acc = 0.f;
        #pragma unroll 8
        for (int j = 0; j < 128; ++j) {
            float h = fmaxf(fmaf(a0, sW1[j], fmaf(a1, sW1[128 + j], fmaf(a2, sW1[256 + j], sb1[j]))), 0.f);
            acc = fmaf(h, sW2[j * 64 + lane], acc);
        }
        t[(size_t)i * 64 + lane] = acc;
    }
}

// Layer-2 gather + relu + fused mean pool.
// 16 lanes per node (float4 over 64 features), 4 nodes/wave, 4-edge unroll -> MLP 16/wave.
__global__ void k_gather2(const int* __restrict__ rs, const int* __restrict__ eidx,
                          const float* __restrict__ enorm, const float4* __restrict__ t4,
                          const float* __restrict__ dis, const float* __restrict__ b2,
                          float* __restrict__ gacc, int n) {
    __shared__ float sred[256 * 4];
    int tid = threadIdx.x;
    int fl = tid & 15;                              // float4 slot within feature row
    int gid = blockIdx.x * (blockDim.x >> 4) + (tid >> 4);
    int ng = gridDim.x * (blockDim.x >> 4);
    float4 b2v = ((const float4*)b2)[fl];
    float4 accg = make_float4(0.f, 0.f, 0.f, 0.f);

    for (int i = gid; i < n; i += ng) {
        float di = dis[i], d2 = di * di;
        float4 self = t4[(size_t)i * 16 + fl];
        float4 acc = make_float4(self.x * d2, self.y * d2, self.z * d2, self.w * d2);
        int p = rs[i], p1 = rs[i + 1];
        for (; p + 3 < p1; p += 4) {
            int s0 = eidx[p], s1 = eidx[p + 1], s2 = eidx[p + 2], s3 = eidx[p + 3];
            float n0 = enorm[p], n1 = enorm[p + 1], n2 = enorm[p + 2], n3 = enorm[p + 3];
            float4 v0 = t4[(size_t)s0 * 16 + fl];
            float4 v1 = t4[(size_t)s1 * 16 + fl];
            float4 v2 = t4[(size_t)s2 * 16 + fl];
            float4 v3 = t4[(size_t)s3 * 16 + fl];
            acc.x = fmaf(v0.x, n0, acc.x); acc.y = fmaf(v0.y, n0, acc.y);
            acc.z = fmaf(v0.z, n0, acc.z); acc.w = fmaf(v0.w, n0, acc.w);
            acc.x = fmaf(v1.x, n1, acc.x); acc.y = fmaf(v1.y, n1, acc.y);
            acc.z = fmaf(v1.z, n1, acc.z); acc.w = fmaf(v1.w, n1, acc.w);
            acc.x = fmaf(v2.x, n2, acc.x); acc.y = fmaf(v2.y, n2, acc.y);
            acc.z = fmaf(v2.z, n2, acc.z); acc.w = fmaf(v2.w, n2, acc.w);
            acc.x = fmaf(v3.x, n3, acc.x); acc.y = fmaf(v3.y, n3, acc.y);
            acc.z = fmaf(v3.z, n3, acc.z); acc.w = fmaf(v3.w, n3, acc.w);
        }
        for (; p < p1; ++p) {
            int s = eidx[p];
            float nm = enorm[p];
            float4 v = t4[(size_t)s * 16 + fl];
            acc.x = fmaf(v.x, nm, acc.x); acc.y = fmaf(v.y, nm, acc.y);
            acc.z = fmaf(v.z, nm, acc.z); acc.w = fmaf(v.w, nm, acc.w);
        }
        accg.x += fmaxf(acc.x + b2v.x, 0.f);
        accg.y += fmaxf(acc.y + b2v.y, 0.f);
        accg.z += fmaxf(acc.z + b2v.z, 0.f);
        accg.w += fmaxf(acc.w + b2v.w, 0.f);
    }

    // Block reduction: sred[group*64 + feature] layout, then 64 atomics per block.
    sred[tid * 4 + 0] = accg.x;
    sred[tid * 4 + 1] = accg.y;
    sred[tid * 4 + 2] = accg.z;
    sred[tid * 4 + 3] = accg.w;
    __syncthreads();
    if (tid < 64) {
        float v = 0.f;
        #pragma unroll
        for (int g = 0; g < 16; ++g) v += sred[g * 64 + tid];
        atomicAdd(&gacc[tid], v);
    }
}

// out[c] = (1/N) * sum_k g[k] * Wfc[k,c] + bfc[c]; single wave.
__global__ void k_final(const float* __restrict__ g_accum, const float* __restrict__ Wfc,
                        const float* __restrict__ bfc, float* __restrict__ out, float inv_n) {
    int lane = threadIdx.x;   // 0..63
    float gk = g_accum[lane] * inv_n;
    #pragma unroll
    for (int c = 0; c < 3; ++c) {
        float p = gk * Wfc[lane * 3 + c];
        #pragma unroll
        for (int off = 32; off > 0; off >>= 1) p += __shfl_down(p, off);
        if (lane == 0) out[c] = p + bfc[c];
    }
}

extern "C" void kernel_launch(void* const* d_in, const int* in_sizes, int n_in,
                              void* d_out, int out_size, void* d_ws, size_t ws_size,
                              hipStream_t stream) {
    const float* x   = (const float*)d_in[0];
    const int*   ei  = (const int*)d_in[1];
    const float* W1  = (const float*)d_in[2];
    const float* b1  = (const float*)d_in[3];
    const float* W2  = (const float*)d_in[4];
    const float* b2  = (const float*)d_in[5];
    const float* Wfc = (const float*)d_in[6];
    const float* bfc = (const float*)d_in[7];

    const int N = in_sizes[0] / 3;      // 50000
    const int E = in_sizes[1] / 2;      // 600000
    const int* src = ei;
    const int* dst = ei + E;

    // Workspace layout (4B units):
    //   dis   : N        @ 0
    //   cnt   : N (int)  @ N        (zeroed)
    //   gacc  : 64       @ 2N       (zeroed)
    //   rs    : N+1(int) @ 2N+64
    //   cur   : N (int)  @ 3N+80    (padded)
    //   eidx  : E (int)  @ 4N+80
    //   enorm : E        @ 4N+80+E
    //   t     : 64N      @ 4N+80+2E (16B-aligned for float4)
    float* ws = (float*)d_ws;
    float* dis   = ws;
    int*   cnt   = (int*)(ws + (size_t)N);
    float* gacc  = ws + (size_t)2 * N;
    int*   rs    = (int*)(ws + (size_t)2 * N + 64);
    int*   cur   = (int*)(ws + (size_t)3 * N + 80);
    int*   eidx  = (int*)(ws + (size_t)4 * N + 80);
    float* enorm = ws + (size_t)4 * N + 80 + (size_t)E;
    float* t     = ws + (size_t)4 * N + 80 + (size_t)2 * E;

    // zero cnt + gacc (contiguous)
    hipMemsetAsync(cnt, 0, ((size_t)N + 64) * sizeof(float), stream);

    k_count<<<1024, 256, 0, stream>>>(dst, cnt, E);
    k_scan<<<1, SCAN_THREADS, 0, stream>>>(cnt, rs, cur, dis, N);
    k_csr<<<1024, 256, 0, stream>>>(src, dst, dis, cur, eidx, enorm, E);
    k_node_t<<<1024, 256, 0, stream>>>(x, dis, rs, eidx, enorm, W1, b1, W2, t, N);
    k_gather2<<<2048, 256, 0, stream>>>(rs, eidx, enorm, (const float4*)t, dis, b2, gacc, N);
    k_final<<<1, 64, 0, stream>>>(gacc, Wfc, bfc, (float*)d_out, 1.0f / (float)N);
}

// Round 4
// 228.821 us; speedup vs baseline: 2.6272x; 1.5200x over previous
//
#include <hip/hip_runtime.h>

// GCN 2-layer + mean-pool + FC for MI355X (gfx950).
// Round 4: replace single-block scan (133us, occupancy 0.14%) with a
// two-kernel hierarchical scan (block reduce -> redundant block-sum scan +
// local scan). Everything else unchanged from round 3.
//
// Pipeline:
//   cnt = indeg
//   bsum[b] = sum of cnt chunk b; scan2: rs/cur = exclusive scan, dis = rsqrt(cnt+1)
//   csr: eidx[pos]=src, enorm[pos]=dis[s]*dis[d]
//   node: a(i) = gather_x + x[i]*dis^2 ; t[i,:] = relu(a@W1+b1)@W2  (weights in LDS)
//   gather2: h2[i,:]=relu(sum t[s,:]*enorm + t[i,:]*dis^2 + b2); gacc += colsum(h2)
//   out = gacc/N @ Wfc + bfc

__global__ void k_count(const int* __restrict__ dst, int* __restrict__ cnt, int E) {
    for (int e = blockIdx.x * blockDim.x + threadIdx.x; e < E; e += gridDim.x * blockDim.x)
        atomicAdd(&cnt[dst[e]], 1);
}

// Phase A: per-block (256-elem chunk) reduction of cnt -> bsum[block].
__global__ void k_bsum(const int* __restrict__ cnt, int* __restrict__ bsum, int n) {
    __shared__ int red[256];
    int tid = threadIdx.x;
    int i = blockIdx.x * 256 + tid;
    red[tid] = (i < n) ? cnt[i] : 0;
    __syncthreads();
    #pragma unroll
    for (int off = 128; off; off >>= 1) {
        if (tid < off) red[tid] += red[tid + off];
        __syncthreads();
    }
    if (tid == 0) bsum[blockIdx.x] = red[0];
}

// Phase B: each block redundantly scans bsum (nb<=256), then scans its own
// 256-elem cnt chunk in LDS; writes rs, cur, dis. rs[n]=E written by thread 0.
__global__ void k_scan2(const int* __restrict__ cnt, const int* __restrict__ bsum,
                        int nb, int* __restrict__ rs, int* __restrict__ cur,
                        float* __restrict__ dis, int n, int Etot) {
    __shared__ int sb[256];
    __shared__ int sc[256];
    int tid = threadIdx.x;
    sb[tid] = (tid < nb) ? bsum[tid] : 0;
    __syncthreads();
    #pragma unroll
    for (int off = 1; off < 256; off <<= 1) {
        int v = (tid >= off) ? sb[tid - off] : 0;
        __syncthreads();
        sb[tid] += v;
        __syncthreads();
    }
    int boff = (blockIdx.x > 0) ? sb[blockIdx.x - 1] : 0;

    int i = blockIdx.x * 256 + tid;
    int c = (i < n) ? cnt[i] : 0;
    sc[tid] = c;
    __syncthreads();
    #pragma unroll
    for (int off = 1; off < 256; off <<= 1) {
        int v = (tid >= off) ? sc[tid - off] : 0;
        __syncthreads();
        sc[tid] += v;
        __syncthreads();
    }
    if (i < n) {
        int r = boff + sc[tid] - c;   // exclusive prefix
        rs[i] = r;
        cur[i] = r;
        dis[i] = rsqrtf((float)c + 1.0f);
    }
    if (i == 0) rs[n] = Etot;
}

// Pure CSR scatter (int cursor atomics only).
__global__ void k_csr(const int* __restrict__ src, const int* __restrict__ dst,
                      const float* __restrict__ dis, int* __restrict__ cur,
                      int* __restrict__ eidx, float* __restrict__ enorm, int E) {
    for (int e = blockIdx.x * blockDim.x + threadIdx.x; e < E; e += gridDim.x * blockDim.x) {
        int s = src[e], d = dst[e];
        int pos = atomicAdd(&cur[d], 1);
        eidx[pos] = s;
        enorm[pos] = dis[s] * dis[d];
    }
}

// Fused: layer-1 gather (lane-per-edge + shfl reduce) + MLP to t.
// One wave per node; lane k owns output feature k. W1/b1/W2 in LDS (34 KB).
__global__ void k_node_t(const float* __restrict__ x, const float* __restrict__ dis,
                         const int* __restrict__ rs, const int* __restrict__ eidx,
                         const float* __restrict__ enorm,
                         const float* __restrict__ W1, const float* __restrict__ b1,
                         const float* __restrict__ W2,
                         float* __restrict__ t, int n) {
    __shared__ float sW1[3 * 128];
    __shared__ float sb1[128];
    __shared__ float sW2[128 * 64];
    for (int i = threadIdx.x; i < 3 * 128;  i += blockDim.x) sW1[i] = W1[i];
    for (int i = threadIdx.x; i < 128;      i += blockDim.x) sb1[i] = b1[i];
    for (int i = threadIdx.x; i < 128 * 64; i += blockDim.x) sW2[i] = W2[i];
    __syncthreads();

    int lane = threadIdx.x & 63;
    int gw = (blockIdx.x * blockDim.x + threadIdx.x) >> 6;
    int nw = (gridDim.x * blockDim.x) >> 6;
    for (int i = gw; i < n; i += nw) {
        int p0 = rs[i], p1 = rs[i + 1];
        float a0 = 0.f, a1 = 0.f, a2 = 0.f;
        for (int p = p0 + lane; p < p1; p += 64) {
            int s = eidx[p];
            float nm = enorm[p];
            a0 = fmaf(x[3 * s + 0], nm, a0);
            a1 = fmaf(x[3 * s + 1], nm, a1);
            a2 = fmaf(x[3 * s + 2], nm, a2);
        }
        #pragma unroll
        for (int m = 32; m; m >>= 1) {
            a0 += __shfl_xor(a0, m);
            a1 += __shfl_xor(a1, m);
            a2 += __shfl_xor(a2, m);
        }
        float di = dis[i], d2 = di * di;
        a0 = fmaf(x[3 * i + 0], d2, a0);
        a1 = fmaf(x[3 * i + 1], d2, a1);
        a2 = fmaf(x[3 * i + 2], d2, a2);
        float acc = 0.f;
        #pragma unroll 8
        for (int j = 0; j < 128; ++j) {
            float h = fmaxf(fmaf(a0, sW1[j], fmaf(a1, sW1[128 + j], fmaf(a2, sW1[256 + j], sb1[j]))), 0.f);
            acc = fmaf(h, sW2[j * 64 + lane], acc);
        }
        t[(size_t)i * 64 + lane] = acc;
    }
}

// Layer-2 gather + relu + fused mean pool.
// 16 lanes per node (float4 over 64 features), 4 nodes/wave, 4-edge unroll -> MLP 16/wave.
__global__ void k_gather2(const int* __restrict__ rs, const int* __restrict__ eidx,
                          const float* __restrict__ enorm, const float4* __restrict__ t4,
                          const float* __restrict__ dis, const float* __restrict__ b2,
                          float* __restrict__ gacc, int n) {
    __shared__ float sred[256 * 4];
    int tid = threadIdx.x;
    int fl = tid & 15;                              // float4 slot within feature row
    int gid = blockIdx.x * (blockDim.x >> 4) + (tid >> 4);
    int ng = gridDim.x * (blockDim.x >> 4);
    float4 b2v = ((const float4*)b2)[fl];
    float4 accg = make_float4(0.f, 0.f, 0.f, 0.f);

    for (int i = gid; i < n; i += ng) {
        float di = dis[i], d2 = di * di;
        float4 self = t4[(size_t)i * 16 + fl];
        float4 acc = make_float4(self.x * d2, self.y * d2, self.z * d2, self.w * d2);
        int p = rs[i], p1 = rs[i + 1];
        for (; p + 3 < p1; p += 4) {
            int s0 = eidx[p], s1 = eidx[p + 1], s2 = eidx[p + 2], s3 = eidx[p + 3];
            float n0 = enorm[p], n1 = enorm[p + 1], n2 = enorm[p + 2], n3 = enorm[p + 3];
            float4 v0 = t4[(size_t)s0 * 16 + fl];
            float4 v1 = t4[(size_t)s1 * 16 + fl];
            float4 v2 = t4[(size_t)s2 * 16 + fl];
            float4 v3 = t4[(size_t)s3 * 16 + fl];
            acc.x = fmaf(v0.x, n0, acc.x); acc.y = fmaf(v0.y, n0, acc.y);
            acc.z = fmaf(v0.z, n0, acc.z); acc.w = fmaf(v0.w, n0, acc.w);
            acc.x = fmaf(v1.x, n1, acc.x); acc.y = fmaf(v1.y, n1, acc.y);
            acc.z = fmaf(v1.z, n1, acc.z); acc.w = fmaf(v1.w, n1, acc.w);
            acc.x = fmaf(v2.x, n2, acc.x); acc.y = fmaf(v2.y, n2, acc.y);
            acc.z = fmaf(v2.z, n2, acc.z); acc.w = fmaf(v2.w, n2, acc.w);
            acc.x = fmaf(v3.x, n3, acc.x); acc.y = fmaf(v3.y, n3, acc.y);
            acc.z = fmaf(v3.z, n3, acc.z); acc.w = fmaf(v3.w, n3, acc.w);
        }
        for (; p < p1; ++p) {
            int s = eidx[p];
            float nm = enorm[p];
            float4 v = t4[(size_t)s * 16 + fl];
            acc.x = fmaf(v.x, nm, acc.x); acc.y = fmaf(v.y, nm, acc.y);
            acc.z = fmaf(v.z, nm, acc.z); acc.w = fmaf(v.w, nm, acc.w);
        }
        accg.x += fmaxf(acc.x + b2v.x, 0.f);
        accg.y += fmaxf(acc.y + b2v.y, 0.f);
        accg.z += fmaxf(acc.z + b2v.z, 0.f);
        accg.w += fmaxf(acc.w + b2v.w, 0.f);
    }

    // Block reduction: sred[group*64 + feature] layout, then 64 atomics per block.
    sred[tid * 4 + 0] = accg.x;
    sred[tid * 4 + 1] = accg.y;
    sred[tid * 4 + 2] = accg.z;
    sred[tid * 4 + 3] = accg.w;
    __syncthreads();
    if (tid < 64) {
        float v = 0.f;
        #pragma unroll
        for (int g = 0; g < 16; ++g) v += sred[g * 64 + tid];
        atomicAdd(&gacc[tid], v);
    }
}

// out[c] = (1/N) * sum_k g[k] * Wfc[k,c] + bfc[c]; single wave.
__global__ void k_final(const float* __restrict__ g_accum, const float* __restrict__ Wfc,
                        const float* __restrict__ bfc, float* __restrict__ out, float inv_n) {
    int lane = threadIdx.x;   // 0..63
    float gk = g_accum[lane] * inv_n;
    #pragma unroll
    for (int c = 0; c < 3; ++c) {
        float p = gk * Wfc[lane * 3 + c];
        #pragma unroll
        for (int off = 32; off > 0; off >>= 1) p += __shfl_down(p, off);
        if (lane == 0) out[c] = p + bfc[c];
    }
}

extern "C" void kernel_launch(void* const* d_in, const int* in_sizes, int n_in,
                              void* d_out, int out_size, void* d_ws, size_t ws_size,
                              hipStream_t stream) {
    const float* x   = (const float*)d_in[0];
    const int*   ei  = (const int*)d_in[1];
    const float* W1  = (const float*)d_in[2];
    const float* b1  = (const float*)d_in[3];
    const float* W2  = (const float*)d_in[4];
    const float* b2  = (const float*)d_in[5];
    const float* Wfc = (const float*)d_in[6];
    const float* bfc = (const float*)d_in[7];

    const int N = in_sizes[0] / 3;      // 50000
    const int E = in_sizes[1] / 2;      // 600000
    const int* src = ei;
    const int* dst = ei + E;
    const int NB = (N + 255) / 256;     // 196 scan blocks (must be <= 256)

    // Workspace layout (4B units):
    //   dis   : N        @ 0
    //   cnt   : N (int)  @ N        (zeroed)
    //   gacc  : 64       @ 2N       (zeroed)
    //   rs    : N+1(int) @ 2N+64
    //   cur   : N (int)  @ 3N+80
    //   bsum  : 256(int) @ 4N+80
    //   eidx  : E (int)  @ 4N+336
    //   enorm : E        @ 4N+336+E
    //   t     : 64N      @ 4N+336+2E (16B-aligned for float4)
    float* ws = (float*)d_ws;
    float* dis   = ws;
    int*   cnt   = (int*)(ws + (size_t)N);
    float* gacc  = ws + (size_t)2 * N;
    int*   rs    = (int*)(ws + (size_t)2 * N + 64);
    int*   cur   = (int*)(ws + (size_t)3 * N + 80);
    int*   bsum  = (int*)(ws + (size_t)4 * N + 80);
    int*   eidx  = (int*)(ws + (size_t)4 * N + 336);
    float* enorm = ws + (size_t)4 * N + 336 + (size_t)E;
    float* t     = ws + (size_t)4 * N + 336 + (size_t)2 * E;

    // zero cnt + gacc (contiguous)
    hipMemsetAsync(cnt, 0, ((size_t)N + 64) * sizeof(float), stream);

    k_count<<<1024, 256, 0, stream>>>(dst, cnt, E);
    k_bsum<<<NB, 256, 0, stream>>>(cnt, bsum, N);
    k_scan2<<<NB, 256, 0, stream>>>(cnt, bsum, NB, rs, cur, dis, N, E);
    k_csr<<<1024, 256, 0, stream>>>(src, dst, dis, cur, eidx, enorm, E);
    k_node_t<<<1024, 256, 0, stream>>>(x, dis, rs, eidx, enorm, W1, b1, W2, t, N);
    k_gather2<<<2048, 256, 0, stream>>>(rs, eidx, enorm, (const float4*)t, dis, b2, gacc, N);
    k_final<<<1, 64, 0, stream>>>(gacc, Wfc, bfc, (float*)d_out, 1.0f / (float)N);
}

// Round 5
// 155.629 us; speedup vs baseline: 3.8628x; 1.4703x over previous
//
#include <hip/hip_runtime.h>

// GCN 2-layer + mean-pool + FC for MI355X (gfx950).
// Round 5: kill the 64x-redundant hidden-layer compute in k_node_t.
// Split into k_aggx (light layer-1 gather -> a[i], 3 floats) and k_mlp
// (register-blocked tiled VALU GEMM: 64-node tile, H^T in LDS, 4x4 acc/thread).
//
// Pipeline:
//   cnt = indeg; bsum+scan2 -> rs/cur, dis = rsqrt(cnt+1)
//   csr: eidx[pos]=src, enorm[pos]=dis[s]*dis[d]
//   aggx[i] = sum_{s in N(i)} x[s]*enorm + x[i]*dis^2     (3 floats/node)
//   mlp:  t[i,:] = relu(aggx[i] @ W1 + b1) @ W2           (tiled, no redundancy)
//   gather2: h2[i,:]=relu(sum t[s,:]*enorm + t[i,:]*dis^2 + b2); gacc += colsum
//   out = gacc/N @ Wfc + bfc

__global__ void k_count(const int* __restrict__ dst, int* __restrict__ cnt, int E) {
    for (int e = blockIdx.x * blockDim.x + threadIdx.x; e < E; e += gridDim.x * blockDim.x)
        atomicAdd(&cnt[dst[e]], 1);
}

// Phase A: per-block (256-elem chunk) reduction of cnt -> bsum[block].
__global__ void k_bsum(const int* __restrict__ cnt, int* __restrict__ bsum, int n) {
    __shared__ int red[256];
    int tid = threadIdx.x;
    int i = blockIdx.x * 256 + tid;
    red[tid] = (i < n) ? cnt[i] : 0;
    __syncthreads();
    #pragma unroll
    for (int off = 128; off; off >>= 1) {
        if (tid < off) red[tid] += red[tid + off];
        __syncthreads();
    }
    if (tid == 0) bsum[blockIdx.x] = red[0];
}

// Phase B: each block redundantly scans bsum (nb<=256), then scans its own
// 256-elem cnt chunk in LDS; writes rs, cur, dis. rs[n]=E.
__global__ void k_scan2(const int* __restrict__ cnt, const int* __restrict__ bsum,
                        int nb, int* __restrict__ rs, int* __restrict__ cur,
                        float* __restrict__ dis, int n, int Etot) {
    __shared__ int sb[256];
    __shared__ int sc[256];
    int tid = threadIdx.x;
    sb[tid] = (tid < nb) ? bsum[tid] : 0;
    __syncthreads();
    #pragma unroll
    for (int off = 1; off < 256; off <<= 1) {
        int v = (tid >= off) ? sb[tid - off] : 0;
        __syncthreads();
        sb[tid] += v;
        __syncthreads();
    }
    int boff = (blockIdx.x > 0) ? sb[blockIdx.x - 1] : 0;

    int i = blockIdx.x * 256 + tid;
    int c = (i < n) ? cnt[i] : 0;
    sc[tid] = c;
    __syncthreads();
    #pragma unroll
    for (int off = 1; off < 256; off <<= 1) {
        int v = (tid >= off) ? sc[tid - off] : 0;
        __syncthreads();
        sc[tid] += v;
        __syncthreads();
    }
    if (i < n) {
        int r = boff + sc[tid] - c;   // exclusive prefix
        rs[i] = r;
        cur[i] = r;
        dis[i] = rsqrtf((float)c + 1.0f);
    }
    if (i == 0) rs[n] = Etot;
}

// Pure CSR scatter (int cursor atomics only).
__global__ void k_csr(const int* __restrict__ src, const int* __restrict__ dst,
                      const float* __restrict__ dis, int* __restrict__ cur,
                      int* __restrict__ eidx, float* __restrict__ enorm, int E) {
    for (int e = blockIdx.x * blockDim.x + threadIdx.x; e < E; e += gridDim.x * blockDim.x) {
        int s = src[e], d = dst[e];
        int pos = atomicAdd(&cur[d], 1);
        eidx[pos] = s;
        enorm[pos] = dis[s] * dis[d];
    }
}

// Layer-1 aggregate: aggx[i] = sum_{s} x[s]*norm + x[i]*dis^2. 8 lanes/node.
__global__ void k_aggx(const float* __restrict__ x, const float* __restrict__ dis,
                       const int* __restrict__ rs, const int* __restrict__ eidx,
                       const float* __restrict__ enorm, float* __restrict__ aggx, int n) {
    int tid = threadIdx.x;
    int sub = tid & 7;
    int gid = blockIdx.x * (blockDim.x >> 3) + (tid >> 3);
    int ng = gridDim.x * (blockDim.x >> 3);
    for (int i = gid; i < n; i += ng) {
        int p0 = rs[i], p1 = rs[i + 1];
        float a0 = 0.f, a1 = 0.f, a2 = 0.f;
        for (int p = p0 + sub; p < p1; p += 8) {
            int s = eidx[p];
            float nm = enorm[p];
            a0 = fmaf(x[3 * s + 0], nm, a0);
            a1 = fmaf(x[3 * s + 1], nm, a1);
            a2 = fmaf(x[3 * s + 2], nm, a2);
        }
        #pragma unroll
        for (int m = 4; m; m >>= 1) {   // reduce within the 8-lane group
            a0 += __shfl_xor(a0, m);
            a1 += __shfl_xor(a1, m);
            a2 += __shfl_xor(a2, m);
        }
        if (sub == 0) {
            float di = dis[i], d2 = di * di;
            aggx[3 * i + 0] = fmaf(x[3 * i + 0], d2, a0);
            aggx[3 * i + 1] = fmaf(x[3 * i + 1], d2, a1);
            aggx[3 * i + 2] = fmaf(x[3 * i + 2], d2, a2);
        }
    }
}

// Tiled MLP: t[i,:] = relu(a(i)@W1+b1)@W2 for a 64-node tile per block.
// H stored transposed in LDS [k][node]; W2 chunk [k][feat] in LDS.
// Thread (ty,tx) accumulates 4 nodes x 4 features; all LDS traffic is b128.
__global__ __launch_bounds__(256) void k_mlp(const float* __restrict__ aggx,
                                             const float* __restrict__ W1,
                                             const float* __restrict__ b1,
                                             const float* __restrict__ W2,
                                             float* __restrict__ t, int n) {
    __shared__ float sA0[64], sA1[64], sA2[64];
    __shared__ float sW1[3 * 128];
    __shared__ float sb1[128];
    __shared__ float sHT[64][64];   // [k_local][node]
    __shared__ float sW2[64][64];   // [k_local][feat]

    int tid = threadIdx.x;
    int i0 = blockIdx.x * 64;
    if (tid < 128) {
        sW1[tid]       = W1[tid];
        sW1[128 + tid] = W1[128 + tid];
        sW1[256 + tid] = W1[256 + tid];
        sb1[tid]       = b1[tid];
    }
    if (tid < 64) {
        int i = i0 + tid;
        if (i < n) {
            sA0[tid] = aggx[3 * i + 0];
            sA1[tid] = aggx[3 * i + 1];
            sA2[tid] = aggx[3 * i + 2];
        } else {
            sA0[tid] = 0.f; sA1[tid] = 0.f; sA2[tid] = 0.f;
        }
    }
    __syncthreads();

    int tx = tid & 15, ty = tid >> 4;
    int nn0 = ty * 4, f0 = tx * 4;
    float acc[4][4] = {};

    for (int c = 0; c < 2; ++c) {
        // compute H^T chunk: 64x64 = 4096 elems, 16 per thread; k uniform per wave
        #pragma unroll
        for (int j = 0; j < 16; ++j) {
            int idx = tid + 256 * j;
            int kl = idx >> 6, nd = idx & 63;
            int k = c * 64 + kl;
            float h = fmaf(sA0[nd], sW1[k],
                      fmaf(sA1[nd], sW1[128 + k],
                      fmaf(sA2[nd], sW1[256 + k], sb1[k])));
            sHT[kl][nd] = fmaxf(h, 0.f);
        }
        // stage W2 chunk (64x64 floats = 1024 float4)
        const float4* W2c = (const float4*)(W2 + c * 64 * 64);
        float4* sW2v = (float4*)sW2;
        #pragma unroll
        for (int j = 0; j < 4; ++j) sW2v[tid + 256 * j] = W2c[tid + 256 * j];
        __syncthreads();

        #pragma unroll 8
        for (int kl = 0; kl < 64; ++kl) {
            float4 hv = *(const float4*)&sHT[kl][nn0];
            float4 wv = *(const float4*)&sW2[kl][f0];
            acc[0][0] = fmaf(hv.x, wv.x, acc[0][0]);
            acc[0][1] = fmaf(hv.x, wv.y, acc[0][1]);
            acc[0][2] = fmaf(hv.x, wv.z, acc[0][2]);
            acc[0][3] = fmaf(hv.x, wv.w, acc[0][3]);
            acc[1][0] = fmaf(hv.y, wv.x, acc[1][0]);
            acc[1][1] = fmaf(hv.y, wv.y, acc[1][1]);
            acc[1][2] = fmaf(hv.y, wv.z, acc[1][2]);
            acc[1][3] = fmaf(hv.y, wv.w, acc[1][3]);
            acc[2][0] = fmaf(hv.z, wv.x, acc[2][0]);
            acc[2][1] = fmaf(hv.z, wv.y, acc[2][1]);
            acc[2][2] = fmaf(hv.z, wv.z, acc[2][2]);
            acc[2][3] = fmaf(hv.z, wv.w, acc[2][3]);
            acc[3][0] = fmaf(hv.w, wv.x, acc[3][0]);
            acc[3][1] = fmaf(hv.w, wv.y, acc[3][1]);
            acc[3][2] = fmaf(hv.w, wv.z, acc[3][2]);
            acc[3][3] = fmaf(hv.w, wv.w, acc[3][3]);
        }
        __syncthreads();
    }

    #pragma unroll
    for (int nn = 0; nn < 4; ++nn) {
        int i = i0 + nn0 + nn;
        if (i < n) {
            float4 o = make_float4(acc[nn][0], acc[nn][1], acc[nn][2], acc[nn][3]);
            *(float4*)&t[(size_t)i * 64 + f0] = o;
        }
    }
}

// Layer-2 gather + relu + fused mean pool.
// 16 lanes per node (float4 over 64 features), 4 nodes/wave, 4-edge unroll.
__global__ void k_gather2(const int* __restrict__ rs, const int* __restrict__ eidx,
                          const float* __restrict__ enorm, const float4* __restrict__ t4,
                          const float* __restrict__ dis, const float* __restrict__ b2,
                          float* __restrict__ gacc, int n) {
    __shared__ float sred[256 * 4];
    int tid = threadIdx.x;
    int fl = tid & 15;
    int gid = blockIdx.x * (blockDim.x >> 4) + (tid >> 4);
    int ng = gridDim.x * (blockDim.x >> 4);
    float4 b2v = ((const float4*)b2)[fl];
    float4 accg = make_float4(0.f, 0.f, 0.f, 0.f);

    for (int i = gid; i < n; i += ng) {
        float di = dis[i], d2 = di * di;
        float4 self = t4[(size_t)i * 16 + fl];
        float4 acc = make_float4(self.x * d2, self.y * d2, self.z * d2, self.w * d2);
        int p = rs[i], p1 = rs[i + 1];
        for (; p + 3 < p1; p += 4) {
            int s0 = eidx[p], s1 = eidx[p + 1], s2 = eidx[p + 2], s3 = eidx[p + 3];
            float n0 = enorm[p], n1 = enorm[p + 1], n2 = enorm[p + 2], n3 = enorm[p + 3];
            float4 v0 = t4[(size_t)s0 * 16 + fl];
            float4 v1 = t4[(size_t)s1 * 16 + fl];
            float4 v2 = t4[(size_t)s2 * 16 + fl];
            float4 v3 = t4[(size_t)s3 * 16 + fl];
            acc.x = fmaf(v0.x, n0, acc.x); acc.y = fmaf(v0.y, n0, acc.y);
            acc.z = fmaf(v0.z, n0, acc.z); acc.w = fmaf(v0.w, n0, acc.w);
            acc.x = fmaf(v1.x, n1, acc.x); acc.y = fmaf(v1.y, n1, acc.y);
            acc.z = fmaf(v1.z, n1, acc.z); acc.w = fmaf(v1.w, n1, acc.w);
            acc.x = fmaf(v2.x, n2, acc.x); acc.y = fmaf(v2.y, n2, acc.y);
            acc.z = fmaf(v2.z, n2, acc.z); acc.w = fmaf(v2.w, n2, acc.w);
            acc.x = fmaf(v3.x, n3, acc.x); acc.y = fmaf(v3.y, n3, acc.y);
            acc.z = fmaf(v3.z, n3, acc.z); acc.w = fmaf(v3.w, n3, acc.w);
        }
        for (; p < p1; ++p) {
            int s = eidx[p];
            float nm = enorm[p];
            float4 v = t4[(size_t)s * 16 + fl];
            acc.x = fmaf(v.x, nm, acc.x); acc.y = fmaf(v.y, nm, acc.y);
            acc.z = fmaf(v.z, nm, acc.z); acc.w = fmaf(v.w, nm, acc.w);
        }
        accg.x += fmaxf(acc.x + b2v.x, 0.f);
        accg.y += fmaxf(acc.y + b2v.y, 0.f);
        accg.z += fmaxf(acc.z + b2v.z, 0.f);
        accg.w += fmaxf(acc.w + b2v.w, 0.f);
    }

    sred[tid * 4 + 0] = accg.x;
    sred[tid * 4 + 1] = accg.y;
    sred[tid * 4 + 2] = accg.z;
    sred[tid * 4 + 3] = accg.w;
    __syncthreads();
    if (tid < 64) {
        float v = 0.f;
        #pragma unroll
        for (int g = 0; g < 16; ++g) v += sred[g * 64 + tid];
        atomicAdd(&gacc[tid], v);
    }
}

// out[c] = (1/N) * sum_k g[k] * Wfc[k,c] + bfc[c]; single wave.
__global__ void k_final(const float* __restrict__ g_accum, const float* __restrict__ Wfc,
                        const float* __restrict__ bfc, float* __restrict__ out, float inv_n) {
    int lane = threadIdx.x;   // 0..63
    float gk = g_accum[lane] * inv_n;
    #pragma unroll
    for (int c = 0; c < 3; ++c) {
        float p = gk * Wfc[lane * 3 + c];
        #pragma unroll
        for (int off = 32; off > 0; off >>= 1) p += __shfl_down(p, off);
        if (lane == 0) out[c] = p + bfc[c];
    }
}

extern "C" void kernel_launch(void* const* d_in, const int* in_sizes, int n_in,
                              void* d_out, int out_size, void* d_ws, size_t ws_size,
                              hipStream_t stream) {
    const float* x   = (const float*)d_in[0];
    const int*   ei  = (const int*)d_in[1];
    const float* W1  = (const float*)d_in[2];
    const float* b1  = (const float*)d_in[3];
    const float* W2  = (const float*)d_in[4];
    const float* b2  = (const float*)d_in[5];
    const float* Wfc = (const float*)d_in[6];
    const float* bfc = (const float*)d_in[7];

    const int N = in_sizes[0] / 3;      // 50000
    const int E = in_sizes[1] / 2;      // 600000
    const int* src = ei;
    const int* dst = ei + E;
    const int NB = (N + 255) / 256;     // 196 scan blocks (<= 256)

    // Workspace layout (4B units):
    //   dis   : N        @ 0
    //   cnt   : N (int)  @ N        (zeroed)
    //   gacc  : 64       @ 2N       (zeroed)
    //   rs    : N+1(int) @ 2N+64
    //   cur   : N (int)  @ 3N+80
    //   bsum  : 256(int) @ 4N+80
    //   aggx  : 3N       @ 4N+336
    //   eidx  : E (int)  @ 7N+336
    //   enorm : E        @ 7N+336+E
    //   t     : 64N      @ 7N+336+2E  (16B-aligned)
    float* ws = (float*)d_ws;
    float* dis   = ws;
    int*   cnt   = (int*)(ws + (size_t)N);
    float* gacc  = ws + (size_t)2 * N;
    int*   rs    = (int*)(ws + (size_t)2 * N + 64);
    int*   cur   = (int*)(ws + (size_t)3 * N + 80);
    int*   bsum  = (int*)(ws + (size_t)4 * N + 80);
    float* aggx  = ws + (size_t)4 * N + 336;
    int*   eidx  = (int*)(ws + (size_t)7 * N + 336);
    float* enorm = ws + (size_t)7 * N + 336 + (size_t)E;
    float* t     = ws + (size_t)7 * N + 336 + (size_t)2 * E;

    hipMemsetAsync(cnt, 0, ((size_t)N + 64) * sizeof(float), stream);

    k_count<<<1024, 256, 0, stream>>>(dst, cnt, E);
    k_bsum<<<NB, 256, 0, stream>>>(cnt, bsum, N);
    k_scan2<<<NB, 256, 0, stream>>>(cnt, bsum, NB, rs, cur, dis, N, E);
    k_csr<<<1024, 256, 0, stream>>>(src, dst, dis, cur, eidx, enorm, E);
    k_aggx<<<(N * 8 + 255) / 256, 256, 0, stream>>>(x, dis, rs, eidx, enorm, aggx, N);
    k_mlp<<<(N + 63) / 64, 256, 0, stream>>>(aggx, W1, b1, W2, t, N);
    k_gather2<<<2048, 256, 0, stream>>>(rs, eidx, enorm, (const float4*)t, dis, b2, gacc, N);
    k_final<<<1, 64, 0, stream>>>(gacc, Wfc, bfc, (float*)d_out, 1.0f / (float)N);
}